// Round 14
// baseline (64.039 us; speedup 1.0000x reference)
//
#include <hip/hip_runtime.h>

namespace {

constexpr int kB  = 16384;  // rods
constexpr int kNV = 129;    // vertices per rod
constexpr int kNE = 128;    // edges per rod
constexpr int kWPB = 4;     // waves per block
constexpr int kRPW = 2;     // rods per wave (one per 32-lane half)

typedef float v4f __attribute__((ext_vector_type(4)));

struct F3 { float x, y, z; };
struct Q4 { float w, x, y, z; };   // fp32 quaternion

// ---- DPP cross-lane (all VALU, no DS); ctrl is a compile-time constant ----
// wave_shr:1 (0x138): lane i <- i-1 whole-wave
// row_shr:N (0x110+N): lane i <- i-N within 16-lane row (lig<N keep old)
// row_bcast15 (0x142): each row's lane15 -> next row
template<int CTRL>
__device__ __forceinline__ int dpp_i(int x) {
    return __builtin_amdgcn_update_dpp(x, x, CTRL, 0xf, 0xf, false);
}
template<int CTRL>
__device__ __forceinline__ float dpp_f(float x) {
    return __int_as_float(dpp_i<CTRL>(__float_as_int(x)));
}
template<int CTRL>
__device__ __forceinline__ double dpp_d(double x) {
    const long long v = __double_as_longlong(x);
    const int rlo = dpp_i<CTRL>((int)(v & 0xffffffffll));
    const int rhi = dpp_i<CTRL>((int)(v >> 32));
    return __longlong_as_double(((long long)(unsigned int)rlo) | (((long long)rhi) << 32));
}

__device__ __forceinline__ F3 crossf(F3 a, F3 b) {
    return { a.y*b.z - a.z*b.y,
             a.z*b.x - a.x*b.z,
             a.x*b.y - a.y*b.x };
}
__device__ __forceinline__ float dotf(F3 a, F3 b) { return a.x*b.x + a.y*b.y + a.z*b.z; }
__device__ __forceinline__ F3 subf(F3 a, F3 b) { return { a.x-b.x, a.y-b.y, a.z-b.z }; }
// matches ref _normalize: x / max(|x|, 1e-12)
__device__ __forceinline__ F3 nrmf(F3 a) {
    const float s = 1.0f / fmaxf(sqrtf(dotf(a, a)), 1e-12f);
    return { a.x*s, a.y*s, a.z*s };
}
// a (x) b : apply b first, then a
__device__ __forceinline__ Q4 qmul(Q4 a, Q4 b) {
    return { a.w*b.w - a.x*b.x - a.y*b.y - a.z*b.z,
             a.w*b.x + a.x*b.w + a.y*b.z - a.z*b.y,
             a.w*b.y - a.x*b.z + a.y*b.w + a.z*b.x,
             a.w*b.z + a.x*b.y - a.y*b.x + a.z*b.w };
}
template<int CTRL>
__device__ __forceinline__ Q4 dpp_q(Q4 a) {
    return { dpp_f<CTRL>(a.w), dpp_f<CTRL>(a.x), dpp_f<CTRL>(a.y), dpp_f<CTRL>(a.z) };
}
// rotate x by unit quaternion q: x + 2w(v x x) + 2 v x (v x x)
__device__ __forceinline__ F3 qrot(Q4 q, F3 x) {
    const F3 v  = { q.x, q.y, q.z };
    const F3 t  = crossf(v, x);
    const F3 t2 = crossf(v, t);
    return { x.x + 2.0f*(q.w*t.x + t2.x),
             x.y + 2.0f*(q.w*t.y + t2.y),
             x.z + 2.0f*(q.w*t.z + t2.z) };
}
__device__ __forceinline__ void nts4(float* p, float a, float b, float c, float d) {
    v4f v = { a, b, c, d };
    __builtin_nontemporal_store(v, (v4f*)p);
}

__global__ __launch_bounds__(256)
void rod_frames_scan_kernel(const float* __restrict__ verts,   // (B, 129, 3)
                            const float* __restrict__ dinit,   // (B, 3)
                            const float* __restrict__ restL,   // (B, 128)
                            float* __restrict__ out)           // [b_u | b_v | kb]
{
    const int lane = threadIdx.x & 63;
    const int h    = lane & 31;          // position within 32-lane half (one rod)
    const int lig  = lane & 15;          // position within 16-lane DPP row
    const int wid  = blockIdx.x * kWPB + (threadIdx.x >> 6);
    const int b    = wid * kRPW + (lane >> 5);   // rod id

    const float* V  = verts + (size_t)b * (kNV*3);
    const float* vb = V + 12*h;

    // ---- own 15 vertex floats = vertices 4h .. 4h+4 (contiguous 60B/lane);
    //      ALL 4 edges are lane-local, only eP crosses lanes ----
    float w[15];
    #pragma unroll
    for (int t = 0; t < 7; ++t) {
        const float2 tt = *(const float2*)(vb + 2*t);
        w[2*t] = tt.x; w[2*t+1] = tt.y;
    }
    w[14] = vb[14];

    // ---- rest lengths L[4h..4h+3] (16B aligned) ----
    const float4 lt = *(const float4*)(restL + (size_t)b * kNE + 4*h);
    const float Lv[4] = { lt.x, lt.y, lt.z, lt.w };

    // ---- handoff from previous lane: its edge 3 (fp64, exact) + its L[3] ----
    const double e3x = (double)w[12] - (double)w[9];
    const double e3y = (double)w[13] - (double)w[10];
    const double e3z = (double)w[14] - (double)w[11];
    double ePx = dpp_d<0x138>(e3x);   // h==0: garbage, unused (anchor / overridden)
    double ePy = dpp_d<0x138>(e3y);
    double ePz = dpp_d<0x138>(e3z);
    double lp  = (double)dpp_f<0x138>(Lv[3]);

    // ---- loop 1: edges (fp64), kb (fp64 denom), q_k, local prefix chain ----
    F3 Ef[4];
    Q4 Pl[4];
    Q4 qloc = {1.f, 0.f, 0.f, 0.f};
    unsigned am = 0;                  // active mask, bit k = edge 4h+k
    float kbuf[12];

    #pragma unroll
    for (int k = 0; k < 4; ++k) {
        const double edx = (double)w[3*k+3] - (double)w[3*k+0];
        const double edy = (double)w[3*k+4] - (double)w[3*k+1];
        const double edz = (double)w[3*k+5] - (double)w[3*k+2];
        const F3 ef = { (float)edx, (float)edy, (float)edz };
        Ef[k] = ef;

        F3 kb = {0.f, 0.f, 0.f};
        Q4 q  = {1.f, 0.f, 0.f, 0.f};
        bool act = (h == 0 && k == 0);          // rod edge 0: anchor
        if (!act) {
            const double denom = lp*(double)Lv[k] + (ePx*edx + ePy*edy + ePz*edz);
            const F3 ePf = { (float)ePx, (float)ePy, (float)ePz };
            const F3 c = crossf(ePf, ef);
            const float rd = 2.0f / (float)denom;
            kb = { c.x*rd, c.y*rd, c.z*rd };
            const float mag = dotf(kb, kb);
            const float inv = 1.0f / (4.0f + mag);
            const float ww  = sqrtf(4.0f * inv);
            if (1.0f - ww > 1e-6f) {
                act = true;
                const float sp = sqrtf(mag * inv);                 // sinPhi
                const float as = sp / fmaxf(sqrtf(mag), 1e-12f);   // sinPhi/|kb|
                q = { ww, kb.x*as, kb.y*as, kb.z*as };
            }
        }
        if (act) am |= (1u << k);
        qloc = (k == 0) ? q : qmul(q, qloc);
        Pl[k] = qloc;

        kbuf[3*k+0] = kb.x; kbuf[3*k+1] = kb.y; kbuf[3*k+2] = kb.z;

        ePx = edx; ePy = edy; ePz = edz;
        lp  = (double)Lv[k];
    }

    // ---- kb stores: 3x 16B-aligned NT float4 (48B contiguous per lane) ----
    float* bu  = out + (size_t)b * (kNE*3) + 12*h;
    float* bv  = bu  + (size_t)kB * (kNE*3);
    float* kbo = bv  + (size_t)kB * (kNE*3);
    nts4(kbo + 0, kbuf[0], kbuf[1], kbuf[2],  kbuf[3]);
    nts4(kbo + 4, kbuf[4], kbuf[5], kbuf[6],  kbuf[7]);
    nts4(kbo + 8, kbuf[8], kbuf[9], kbuf[10], kbuf[11]);

    // ---- 32-lane inclusive scan of quaternion products per half, all DPP:
    //      row_shr 1,2,4,8 + row_bcast15 (rows 1,3 only -> rod-local) ----
    Q4 s = qloc;
    { const Q4 t = dpp_q<0x111>(s); if (lig >= 1) s = qmul(s, t); }
    { const Q4 t = dpp_q<0x112>(s); if (lig >= 2) s = qmul(s, t); }
    { const Q4 t = dpp_q<0x114>(s); if (lig >= 4) s = qmul(s, t); }
    { const Q4 t = dpp_q<0x118>(s); if (lig >= 8) s = qmul(s, t); }
    { const Q4 t = dpp_q<0x142>(s); if ((lane >> 4) & 1) s = qmul(s, t); }
    Q4 ex = dpp_q<0x138>(s);                   // exclusive shift (whole wave)
    if (h == 0) ex = {1.f, 0.f, 0.f, 0.f};     // half boundary: identity

    // ---- last-active-index max-scan (same DPP structure, int) ----
    const int hk = am ? (4*h + (31 - __builtin_clz(am))) : -1;
    int m = hk;
    { const int t = dpp_i<0x111>(m); if (lig >= 1) m = max(m, t); }
    { const int t = dpp_i<0x112>(m); if (lig >= 2) m = max(m, t); }
    { const int t = dpp_i<0x114>(m); if (lig >= 4) m = max(m, t); }
    { const int t = dpp_i<0x118>(m); if (lig >= 8) m = max(m, t); }
    { const int t = dpp_i<0x142>(m); if ((lane >> 4) & 1) m = max(m, t); }
    int exm = dpp_i<0x138>(m);
    if (h == 0) exm = -1;

    // ---- u0 per rod (uniform within half; L1-broadcast loads) ----
    const F3 dvf = { dinit[3*b+0], dinit[3*b+1], dinit[3*b+2] };
    const F3 p0  = { V[0], V[1], V[2] };
    const F3 p1  = { V[3], V[4], V[5] };
    const F3 e0f = subf(p1, p0);
    const F3 u0  = nrmf(crossf(crossf(e0f, dvf), e0f));
    const F3 u0p = qrot(ex, u0);    // R(Pl_k (x) ex) u0 == R(Pl_k)(R(ex) u0)

    // ---- v-carry: j = last active edge <= i; rare cold reload if j != i ----
    int jv[4];
    bool anyj = false;
    #pragma unroll
    for (int k = 0; k < 4; ++k) {
        const unsigned lm = am & ((2u << k) - 1u);
        const int j = lm ? (4*h + (31 - __builtin_clz(lm))) : exm;
        jv[k] = j;
        anyj |= (j != 4*h + k);
    }
    if (__any(anyj)) {
        #pragma unroll
        for (int k = 0; k < 4; ++k) {
            if (jv[k] != 4*h + k) {
                const float* pj = V + 3*jv[k];
                const double dx = (double)pj[3] - (double)pj[0];
                const double dy = (double)pj[4] - (double)pj[1];
                const double dz = (double)pj[5] - (double)pj[2];
                Ef[k] = { (float)dx, (float)dy, (float)dz };
            }
        }
    }

    // ---- loop 2: u_k, v_k into 12-float buffers, then 16B NT stores ----
    float ub[12], vbuf[12];
    #pragma unroll
    for (int k = 0; k < 4; ++k) {
        const F3 u = qrot(Pl[k], u0p);
        const F3 v = nrmf(crossf(Ef[k], u));
        ub[3*k+0] = u.x; ub[3*k+1] = u.y; ub[3*k+2] = u.z;
        vbuf[3*k+0] = v.x; vbuf[3*k+1] = v.y; vbuf[3*k+2] = v.z;
    }
    nts4(bu + 0, ub[0], ub[1], ub[2],  ub[3]);
    nts4(bu + 4, ub[4], ub[5], ub[6],  ub[7]);
    nts4(bu + 8, ub[8], ub[9], ub[10], ub[11]);
    nts4(bv + 0, vbuf[0], vbuf[1], vbuf[2],  vbuf[3]);
    nts4(bv + 4, vbuf[4], vbuf[5], vbuf[6],  vbuf[7]);
    nts4(bv + 8, vbuf[8], vbuf[9], vbuf[10], vbuf[11]);
}

} // namespace

extern "C" void kernel_launch(void* const* d_in, const int* in_sizes, int n_in,
                              void* d_out, int out_size, void* d_ws, size_t ws_size,
                              hipStream_t stream)
{
    const float* verts = (const float*)d_in[0];
    const float* dinit = (const float*)d_in[1];
    const float* restL = (const float*)d_in[2];
    float* out = (float*)d_out;

    dim3 grid(kB / (kWPB * kRPW));   // 1024 blocks x 4 waves x 2 rods = 16384 rods
    dim3 block(64 * kWPB);
    hipLaunchKernelGGL(rod_frames_scan_kernel, grid, block, 0, stream,
                       verts, dinit, restL, out);
}

// Round 15
// 27.687 us; speedup vs baseline: 2.3130x; 2.3130x over previous
//
#include <hip/hip_runtime.h>

namespace {

constexpr int kB  = 16384;  // rods
constexpr int kNV = 129;    // vertices per rod
constexpr int kNE = 128;    // edges per rod
constexpr int kRPB = 4;     // rods (= waves) per block

typedef float v2f __attribute__((ext_vector_type(2)));   // NT-store-compatible

struct F3 { float x, y, z; };
struct Q4 { float w, x, y, z; };   // fp32 quaternion

// ---- fast (1-ulp) transcendentals: outputs feed 2%-threshold kb / 0.02-threshold u,v ----
__device__ __forceinline__ float frcp(float x) { return __builtin_amdgcn_rcpf(x); }
__device__ __forceinline__ float frsq(float x) { return __builtin_amdgcn_rsqf(x); }

// ---- DPP cross-lane (all VALU, no DS); ctrl is a compile-time constant ----
// wave_shr:1 (0x138): lane i <- i-1 whole-wave; wave_shl:1 (0x130): lane i <- i+1
// row_shr:N (0x110+N): lane i <- i-N within 16-lane row
// row_bcast15 (0x142): row's lane15 -> next row; row_bcast31 (0x143): lane31 -> rows 2,3
template<int CTRL>
__device__ __forceinline__ int dpp_i(int x) {
    return __builtin_amdgcn_update_dpp(x, x, CTRL, 0xf, 0xf, false);
}
template<int CTRL>
__device__ __forceinline__ float dpp_f(float x) {
    return __int_as_float(dpp_i<CTRL>(__float_as_int(x)));
}
__device__ __forceinline__ float dpp_up1(float x) { return dpp_f<0x138>(x); }
__device__ __forceinline__ float dpp_dn1(float x) { return dpp_f<0x130>(x); }
__device__ __forceinline__ double dpp_up1_d(double x) {
    const long long v = __double_as_longlong(x);
    const int rlo = dpp_i<0x138>((int)(v & 0xffffffffll));
    const int rhi = dpp_i<0x138>((int)(v >> 32));
    return __longlong_as_double(((long long)(unsigned int)rlo) | (((long long)rhi) << 32));
}

__device__ __forceinline__ F3 crossf(F3 a, F3 b) {
    return { a.y*b.z - a.z*b.y,
             a.z*b.x - a.x*b.z,
             a.x*b.y - a.y*b.x };
}
__device__ __forceinline__ float dotf(F3 a, F3 b) { return a.x*b.x + a.y*b.y + a.z*b.z; }
__device__ __forceinline__ F3 subf(F3 a, F3 b) { return { a.x-b.x, a.y-b.y, a.z-b.z }; }
// normalize via fast rsqrt (matches ref x/max(|x|,1e-12) to ~1 ulp of rsqrt)
__device__ __forceinline__ F3 nrmf(F3 a) {
    const float s = frsq(fmaxf(dotf(a, a), 1e-24f));
    return { a.x*s, a.y*s, a.z*s };
}
// a (x) b : apply b first, then a
__device__ __forceinline__ Q4 qmul(Q4 a, Q4 b) {
    return { a.w*b.w - a.x*b.x - a.y*b.y - a.z*b.z,
             a.w*b.x + a.x*b.w + a.y*b.z - a.z*b.y,
             a.w*b.y - a.x*b.z + a.y*b.w + a.z*b.x,
             a.w*b.z + a.x*b.y - a.y*b.x + a.z*b.w };
}
// rotate x by unit quaternion q: x + 2w(v x x) + 2 v x (v x x)
__device__ __forceinline__ F3 qrot(Q4 q, F3 x) {
    const F3 v  = { q.x, q.y, q.z };
    const F3 t  = crossf(v, x);
    const F3 t2 = crossf(v, t);
    return { x.x + 2.0f*(q.w*t.x + t2.x),
             x.y + 2.0f*(q.w*t.y + t2.y),
             x.z + 2.0f*(q.w*t.z + t2.z) };
}
template<int CTRL>
__device__ __forceinline__ Q4 dpp_q(Q4 a) {
    return { dpp_f<CTRL>(a.w), dpp_f<CTRL>(a.x), dpp_f<CTRL>(a.y), dpp_f<CTRL>(a.z) };
}
// highest set bit index, m != 0
__device__ __forceinline__ int hbit(unsigned long long m) {
    return 63 - __builtin_clzll(m);
}
__device__ __forceinline__ void nts2(float* p, float a, float bq) {
    v2f v = { a, bq };
    __builtin_nontemporal_store(v, (v2f*)p);
}

__global__ __launch_bounds__(256)
void rod_frames_scan_kernel(const float* __restrict__ verts,   // (B, 129, 3)
                            const float* __restrict__ dinit,   // (B, 3)
                            const float* __restrict__ restL,   // (B, 128)
                            float* __restrict__ out)           // [b_u | b_v | kb]
{
    const int wave = threadIdx.x >> 6;
    const int lane = threadIdx.x & 63;
    const int lig  = lane & 15;
    const int b = blockIdx.x * kRPB + wave;

    const int i0 = 2*lane, i1 = 2*lane + 1;

    // ---- per-lane vertex loads: ONLY own 2 vertices (3x float2, 8B aligned) ----
    const float2* V2 = (const float2*)(verts + (size_t)b * (kNV*3));
    const float2 f0 = V2[3*lane + 0];
    const float2 f1 = V2[3*lane + 1];
    const float2 f2 = V2[3*lane + 2];
    const F3 vA = { f0.x, f0.y, f1.x };   // vertex 2l
    const F3 vB = { f1.y, f2.x, f2.y };   // vertex 2l+1

    // ---- wave-uniform reads -> scalar pipe ----
    const int bw = __builtin_amdgcn_readfirstlane(b);
    const float* Vu = verts + (size_t)bw * (kNV*3);
    const F3 vLast = { Vu[kNE*3+0], Vu[kNE*3+1], Vu[kNE*3+2] };   // vertex 128
    const F3 dvf   = { dinit[bw*3+0], dinit[bw*3+1], dinit[bw*3+2] };
    const F3 p0    = { Vu[0], Vu[1], Vu[2] };
    const F3 p1    = { Vu[3], Vu[4], Vu[5] };

    // ---- vC (vertex 2l+2) from neighbor lane via DPP; lane 63 takes vertex 128 ----
    F3 vC = { dpp_dn1(vA.x), dpp_dn1(vA.y), dpp_dn1(vA.z) };
    if (lane == 63) vC = vLast;

    // ---- fp64 edges (exact: fp32 promotes exactly, diffs fit 53 bits) ----
    const double eAdx = (double)vB.x - (double)vA.x;   // e_{2l}
    const double eAdy = (double)vB.y - (double)vA.y;
    const double eAdz = (double)vB.z - (double)vA.z;
    const double eBdx = (double)vC.x - (double)vB.x;   // e_{2l+1}
    const double eBdy = (double)vC.y - (double)vB.y;
    const double eBdz = (double)vC.z - (double)vB.z;
    // e_{2l-1} = previous lane's eB via DPP (bit-identical; lane 0 unused)
    const double ePdx = dpp_up1_d(eBdx);
    const double ePdy = dpp_up1_d(eBdy);
    const double ePdz = dpp_up1_d(eBdz);

    const F3 eAf = { (float)eAdx, (float)eAdy, (float)eAdz };
    const F3 eBf = { (float)eBdx, (float)eBdy, (float)eBdz };
    const F3 ePf = { (float)ePdx, (float)ePdy, (float)ePdz };

    // ---- u0 (identical in every lane), fp32 ----
    const F3 e0f = subf(p1, p0);
    const F3 u0  = nrmf(crossf(crossf(e0f, dvf), e0f));

    // ---- rest lengths: own pair + neighbor's high half via DPP ----
    const float2 Lp = *(const float2*)(restL + (size_t)b*kNE + i0);
    const float lPf = dpp_up1(Lp.y);   // L[i0-1] (lane 0: unused)
    const double lA = (double)Lp.x;
    const double lB = (double)Lp.y;
    const double lP = (double)lPf;

    // ---- per-slot kb (fp64 denom, fp32 numerator), quaternion, activity.
    //      Identity: cosPhi = 2/sqrt(4+mag), sinPhi*normalize(kb) = kb/sqrt(4+mag)
    //      -> whole quaternion = one rsqrt + muls ----
    F3  kb0 = {0.f, 0.f, 0.f};
    Q4  q0  = {1.f, 0.f, 0.f, 0.f};
    bool act0 = (lane == 0);          // index 0 is the u0/v0 anchor
    if (lane > 0) {
        const double denom = lP*lA + (ePdx*eAdx + ePdy*eAdy + ePdz*eAdz);
        const F3 c = crossf(ePf, eAf);
        const float rd = 2.0f * frcp((float)denom);
        kb0 = { c.x*rd, c.y*rd, c.z*rd };
        const float mag = dotf(kb0, kb0);
        const float r   = frsq(4.0f + mag);    // 1/sqrt(4+mag)
        const float w   = 2.0f * r;            // cosPhi
        if (1.0f - w > 1e-6f) {
            act0 = true;
            q0 = { w, kb0.x*r, kb0.y*r, kb0.z*r };
        }
    }

    F3  kb1;
    Q4  q1  = {1.f, 0.f, 0.f, 0.f};
    bool act1 = false;
    {
        const double denom = lA*lB + (eAdx*eBdx + eAdy*eBdy + eAdz*eBdz);
        const F3 c = crossf(eAf, eBf);
        const float rd = 2.0f * frcp((float)denom);
        kb1 = { c.x*rd, c.y*rd, c.z*rd };
        const float mag = dotf(kb1, kb1);
        const float r   = frsq(4.0f + mag);
        const float w   = 2.0f * r;
        if (1.0f - w > 1e-6f) {
            act1 = true;
            q1 = { w, kb1.x*r, kb1.y*r, kb1.z*r };
        }
    }

    // ---- whole-wave inclusive scan of quaternion products, 100% DPP (no DS):
    //      row-local Kogge-Stone (row_shr 1,2,4,8) + row_bcast15 + row_bcast31 ----
    Q4 s = qmul(q1, q0);
    { const Q4 t = dpp_q<0x111>(s); if (lig >= 1) s = qmul(s, t); }
    { const Q4 t = dpp_q<0x112>(s); if (lig >= 2) s = qmul(s, t); }
    { const Q4 t = dpp_q<0x114>(s); if (lig >= 4) s = qmul(s, t); }
    { const Q4 t = dpp_q<0x118>(s); if (lig >= 8) s = qmul(s, t); }
    { const Q4 t = dpp_q<0x142>(s);                    // row_bcast15 -> rows 1,3
      const int row = lane >> 4;
      if (row == 1 || row == 3) s = qmul(s, t); }
    { const Q4 t = dpp_q<0x143>(s);                    // row_bcast31 -> rows 2,3
      if (lane >= 32) s = qmul(s, t); }
    Q4 ex = dpp_q<0x138>(s);                           // wave_shr:1 (exclusive shift)
    if (lane == 0) ex = {1.f, 0.f, 0.f, 0.f};
    const Q4 Qa = qmul(q0, ex);   // composed rotation up to index i0
    const Q4 Qb = s;              // composed rotation up to index i1

    // ---- last-active-index via ballot + clz ----
    const unsigned long long mask0 = __ballot(act0);   // bit l = act at slot 2l
    const unsigned long long mask1 = __ballot(act1);   // bit l = act at slot 2l+1
    const unsigned long long m0a = mask0 & (~0ull >> (63 - lane));          // bits 0..l (nonempty: bit0 set)
    const unsigned long long m1a = lane ? (mask1 & (~0ull >> (64 - lane))) : 0ull; // bits 0..l-1
    const int j0 = max(2*hbit(m0a), m1a ? 2*hbit(m1a)+1 : -1);
    const unsigned long long m1b = mask1 & (~0ull >> (63 - lane));          // bits 0..l
    const int j1 = max(2*hbit(m0a), m1b ? 2*hbit(m1b)+1 : -1);

    // ---- u_i = R(Q_i) u0 ----
    const F3 uA = qrot(Qa, u0);
    const F3 uB = qrot(Qb, u0);

    // ---- edges at j0/j1: almost always own eA/eB; rare wave-uniform gather ----
    F3 ej0 = eAf, ej1 = eBf;
    if (__any((j0 != i0) || (j1 != i1))) {
        const int s0 = j0 >> 1, s1 = j1 >> 1;
        const F3 a0 = { __shfl(eAf.x, s0, 64), __shfl(eAf.y, s0, 64), __shfl(eAf.z, s0, 64) };
        const F3 b0 = { __shfl(eBf.x, s0, 64), __shfl(eBf.y, s0, 64), __shfl(eBf.z, s0, 64) };
        const F3 a1 = { __shfl(eAf.x, s1, 64), __shfl(eAf.y, s1, 64), __shfl(eAf.z, s1, 64) };
        const F3 b1 = { __shfl(eBf.x, s1, 64), __shfl(eBf.y, s1, 64), __shfl(eBf.z, s1, 64) };
        ej0 = (j0 & 1) ? b0 : a0;
        ej1 = (j1 & 1) ? b1 : a1;
    }

    const F3 vvA = nrmf(crossf(ej0, uA));
    const F3 vvB = nrmf(crossf(ej1, uB));

    // ---- coalesced NT stores: 8B/lane contiguous per instruction (full-line WC;
    //      16B/lane-with-stride variants inflate WRITE_SIZE 2x -- R11/R14) ----
    float* bu  = out + (size_t)b * (kNE*3);
    float* bv  = bu  + (size_t)kB * (kNE*3);
    float* kbo = bv  + (size_t)kB * (kNE*3);
    const int o = 6*lane;

    nts2(bu + o    , uA.x, uA.y);
    nts2(bu + o + 2, uA.z, uB.x);
    nts2(bu + o + 4, uB.y, uB.z);

    nts2(bv + o    , vvA.x, vvA.y);
    nts2(bv + o + 2, vvA.z, vvB.x);
    nts2(bv + o + 4, vvB.y, vvB.z);

    nts2(kbo + o    , kb0.x, kb0.y);
    nts2(kbo + o + 2, kb0.z, kb1.x);
    nts2(kbo + o + 4, kb1.y, kb1.z);
}

} // namespace

extern "C" void kernel_launch(void* const* d_in, const int* in_sizes, int n_in,
                              void* d_out, int out_size, void* d_ws, size_t ws_size,
                              hipStream_t stream)
{
    const float* verts = (const float*)d_in[0];
    const float* dinit = (const float*)d_in[1];
    const float* restL = (const float*)d_in[2];
    float* out = (float*)d_out;

    dim3 grid(kB / kRPB);
    dim3 block(64 * kRPB);
    hipLaunchKernelGGL(rod_frames_scan_kernel, grid, block, 0, stream,
                       verts, dinit, restL, out);
}

// Round 16
// 27.470 us; speedup vs baseline: 2.3313x; 1.0079x over previous
//
#include <hip/hip_runtime.h>

namespace {

constexpr int kB  = 16384;  // rods
constexpr int kNV = 129;    // vertices per rod
constexpr int kNE = 128;    // edges per rod
constexpr int kRPB = 16;    // rods (= waves) per block: 1024-thread blocks

typedef float v2f __attribute__((ext_vector_type(2)));   // NT-store-compatible

struct F3 { float x, y, z; };
struct Q4 { float w, x, y, z; };   // fp32 quaternion

// ---- fast (1-ulp) transcendentals: outputs feed 2%-threshold kb / 0.02-threshold u,v ----
__device__ __forceinline__ float frcp(float x) { return __builtin_amdgcn_rcpf(x); }
__device__ __forceinline__ float frsq(float x) { return __builtin_amdgcn_rsqf(x); }

// ---- DPP cross-lane (all VALU, no DS); ctrl is a compile-time constant ----
// wave_shr:1 (0x138): lane i <- i-1 whole-wave; wave_shl:1 (0x130): lane i <- i+1
// row_shr:N (0x110+N): lane i <- i-N within 16-lane row
// row_bcast15 (0x142): row's lane15 -> next row; row_bcast31 (0x143): lane31 -> rows 2,3
template<int CTRL>
__device__ __forceinline__ int dpp_i(int x) {
    return __builtin_amdgcn_update_dpp(x, x, CTRL, 0xf, 0xf, false);
}
template<int CTRL>
__device__ __forceinline__ float dpp_f(float x) {
    return __int_as_float(dpp_i<CTRL>(__float_as_int(x)));
}
__device__ __forceinline__ float dpp_up1(float x) { return dpp_f<0x138>(x); }
__device__ __forceinline__ float dpp_dn1(float x) { return dpp_f<0x130>(x); }
__device__ __forceinline__ double dpp_up1_d(double x) {
    const long long v = __double_as_longlong(x);
    const int rlo = dpp_i<0x138>((int)(v & 0xffffffffll));
    const int rhi = dpp_i<0x138>((int)(v >> 32));
    return __longlong_as_double(((long long)(unsigned int)rlo) | (((long long)rhi) << 32));
}

__device__ __forceinline__ F3 crossf(F3 a, F3 b) {
    return { a.y*b.z - a.z*b.y,
             a.z*b.x - a.x*b.z,
             a.x*b.y - a.y*b.x };
}
__device__ __forceinline__ float dotf(F3 a, F3 b) { return a.x*b.x + a.y*b.y + a.z*b.z; }
__device__ __forceinline__ F3 subf(F3 a, F3 b) { return { a.x-b.x, a.y-b.y, a.z-b.z }; }
// normalize via fast rsqrt (matches ref x/max(|x|,1e-12) to ~1 ulp of rsqrt)
__device__ __forceinline__ F3 nrmf(F3 a) {
    const float s = frsq(fmaxf(dotf(a, a), 1e-24f));
    return { a.x*s, a.y*s, a.z*s };
}
// a (x) b : apply b first, then a
__device__ __forceinline__ Q4 qmul(Q4 a, Q4 b) {
    return { a.w*b.w - a.x*b.x - a.y*b.y - a.z*b.z,
             a.w*b.x + a.x*b.w + a.y*b.z - a.z*b.y,
             a.w*b.y - a.x*b.z + a.y*b.w + a.z*b.x,
             a.w*b.z + a.x*b.y - a.y*b.x + a.z*b.w };
}
// rotate x by unit quaternion q: x + 2w(v x x) + 2 v x (v x x)
__device__ __forceinline__ F3 qrot(Q4 q, F3 x) {
    const F3 v  = { q.x, q.y, q.z };
    const F3 t  = crossf(v, x);
    const F3 t2 = crossf(v, t);
    return { x.x + 2.0f*(q.w*t.x + t2.x),
             x.y + 2.0f*(q.w*t.y + t2.y),
             x.z + 2.0f*(q.w*t.z + t2.z) };
}
template<int CTRL>
__device__ __forceinline__ Q4 dpp_q(Q4 a) {
    return { dpp_f<CTRL>(a.w), dpp_f<CTRL>(a.x), dpp_f<CTRL>(a.y), dpp_f<CTRL>(a.z) };
}
// highest set bit index, m != 0
__device__ __forceinline__ int hbit(unsigned long long m) {
    return 63 - __builtin_clzll(m);
}
__device__ __forceinline__ void nts2(float* p, float a, float bq) {
    v2f v = { a, bq };
    __builtin_nontemporal_store(v, (v2f*)p);
}

__global__ __launch_bounds__(1024)
void rod_frames_scan_kernel(const float* __restrict__ verts,   // (B, 129, 3)
                            const float* __restrict__ dinit,   // (B, 3)
                            const float* __restrict__ restL,   // (B, 128)
                            float* __restrict__ out)           // [b_u | b_v | kb]
{
    const int wave = threadIdx.x >> 6;
    const int lane = threadIdx.x & 63;
    const int lig  = lane & 15;
    const int b = blockIdx.x * kRPB + wave;

    const int i0 = 2*lane, i1 = 2*lane + 1;

    // ---- per-lane vertex loads: ONLY own 2 vertices (3x float2, 8B aligned) ----
    const float2* V2 = (const float2*)(verts + (size_t)b * (kNV*3));
    const float2 f0 = V2[3*lane + 0];
    const float2 f1 = V2[3*lane + 1];
    const float2 f2 = V2[3*lane + 2];
    const F3 vA = { f0.x, f0.y, f1.x };   // vertex 2l
    const F3 vB = { f1.y, f2.x, f2.y };   // vertex 2l+1

    // ---- wave-uniform reads -> scalar pipe ----
    const int bw = __builtin_amdgcn_readfirstlane(b);
    const float* Vu = verts + (size_t)bw * (kNV*3);
    const F3 vLast = { Vu[kNE*3+0], Vu[kNE*3+1], Vu[kNE*3+2] };   // vertex 128
    const F3 dvf   = { dinit[bw*3+0], dinit[bw*3+1], dinit[bw*3+2] };
    const F3 p0    = { Vu[0], Vu[1], Vu[2] };
    const F3 p1    = { Vu[3], Vu[4], Vu[5] };

    // ---- vC (vertex 2l+2) from neighbor lane via DPP; lane 63 takes vertex 128 ----
    F3 vC = { dpp_dn1(vA.x), dpp_dn1(vA.y), dpp_dn1(vA.z) };
    if (lane == 63) vC = vLast;

    // ---- fp64 edges (exact: fp32 promotes exactly, diffs fit 53 bits) ----
    const double eAdx = (double)vB.x - (double)vA.x;   // e_{2l}
    const double eAdy = (double)vB.y - (double)vA.y;
    const double eAdz = (double)vB.z - (double)vA.z;
    const double eBdx = (double)vC.x - (double)vB.x;   // e_{2l+1}
    const double eBdy = (double)vC.y - (double)vB.y;
    const double eBdz = (double)vC.z - (double)vB.z;
    // e_{2l-1} = previous lane's eB via DPP (bit-identical; lane 0 unused)
    const double ePdx = dpp_up1_d(eBdx);
    const double ePdy = dpp_up1_d(eBdy);
    const double ePdz = dpp_up1_d(eBdz);

    const F3 eAf = { (float)eAdx, (float)eAdy, (float)eAdz };
    const F3 eBf = { (float)eBdx, (float)eBdy, (float)eBdz };
    const F3 ePf = { (float)ePdx, (float)ePdy, (float)ePdz };

    // ---- u0 (identical in every lane), fp32 ----
    const F3 e0f = subf(p1, p0);
    const F3 u0  = nrmf(crossf(crossf(e0f, dvf), e0f));

    // ---- rest lengths: own pair + neighbor's high half via DPP ----
    const float2 Lp = *(const float2*)(restL + (size_t)b*kNE + i0);
    const float lPf = dpp_up1(Lp.y);   // L[i0-1] (lane 0: unused)
    const double lA = (double)Lp.x;
    const double lB = (double)Lp.y;
    const double lP = (double)lPf;

    // ---- per-slot kb (fp64 denom, fp32 numerator), quaternion, activity.
    //      Identity: cosPhi = 2/sqrt(4+mag), sinPhi*normalize(kb) = kb/sqrt(4+mag) ----
    F3  kb0 = {0.f, 0.f, 0.f};
    Q4  q0  = {1.f, 0.f, 0.f, 0.f};
    bool act0 = (lane == 0);          // index 0 is the u0/v0 anchor
    if (lane > 0) {
        const double denom = lP*lA + (ePdx*eAdx + ePdy*eAdy + ePdz*eAdz);
        const F3 c = crossf(ePf, eAf);
        const float rd = 2.0f * frcp((float)denom);
        kb0 = { c.x*rd, c.y*rd, c.z*rd };
        const float mag = dotf(kb0, kb0);
        const float r   = frsq(4.0f + mag);    // 1/sqrt(4+mag)
        const float w   = 2.0f * r;            // cosPhi
        if (1.0f - w > 1e-6f) {
            act0 = true;
            q0 = { w, kb0.x*r, kb0.y*r, kb0.z*r };
        }
    }

    F3  kb1;
    Q4  q1  = {1.f, 0.f, 0.f, 0.f};
    bool act1 = false;
    {
        const double denom = lA*lB + (eAdx*eBdx + eAdy*eBdy + eAdz*eBdz);
        const F3 c = crossf(eAf, eBf);
        const float rd = 2.0f * frcp((float)denom);
        kb1 = { c.x*rd, c.y*rd, c.z*rd };
        const float mag = dotf(kb1, kb1);
        const float r   = frsq(4.0f + mag);
        const float w   = 2.0f * r;
        if (1.0f - w > 1e-6f) {
            act1 = true;
            q1 = { w, kb1.x*r, kb1.y*r, kb1.z*r };
        }
    }

    // ---- whole-wave inclusive scan of quaternion products, 100% DPP (no DS) ----
    Q4 s = qmul(q1, q0);
    { const Q4 t = dpp_q<0x111>(s); if (lig >= 1) s = qmul(s, t); }
    { const Q4 t = dpp_q<0x112>(s); if (lig >= 2) s = qmul(s, t); }
    { const Q4 t = dpp_q<0x114>(s); if (lig >= 4) s = qmul(s, t); }
    { const Q4 t = dpp_q<0x118>(s); if (lig >= 8) s = qmul(s, t); }
    { const Q4 t = dpp_q<0x142>(s);                    // row_bcast15 -> rows 1,3
      const int row = lane >> 4;
      if (row == 1 || row == 3) s = qmul(s, t); }
    { const Q4 t = dpp_q<0x143>(s);                    // row_bcast31 -> rows 2,3
      if (lane >= 32) s = qmul(s, t); }
    Q4 ex = dpp_q<0x138>(s);                           // wave_shr:1 (exclusive shift)
    if (lane == 0) ex = {1.f, 0.f, 0.f, 0.f};
    const Q4 Qa = qmul(q0, ex);   // composed rotation up to index i0
    const Q4 Qb = s;              // composed rotation up to index i1

    // ---- last-active-index via ballot + clz ----
    const unsigned long long mask0 = __ballot(act0);   // bit l = act at slot 2l
    const unsigned long long mask1 = __ballot(act1);   // bit l = act at slot 2l+1
    const unsigned long long m0a = mask0 & (~0ull >> (63 - lane));          // bits 0..l (nonempty: bit0 set)
    const unsigned long long m1a = lane ? (mask1 & (~0ull >> (64 - lane))) : 0ull; // bits 0..l-1
    const int j0 = max(2*hbit(m0a), m1a ? 2*hbit(m1a)+1 : -1);
    const unsigned long long m1b = mask1 & (~0ull >> (63 - lane));          // bits 0..l
    const int j1 = max(2*hbit(m0a), m1b ? 2*hbit(m1b)+1 : -1);

    // ---- u_i = R(Q_i) u0 ----
    const F3 uA = qrot(Qa, u0);
    const F3 uB = qrot(Qb, u0);

    // ---- edges at j0/j1: almost always own eA/eB; rare wave-uniform gather ----
    F3 ej0 = eAf, ej1 = eBf;
    if (__any((j0 != i0) || (j1 != i1))) {
        const int s0 = j0 >> 1, s1 = j1 >> 1;
        const F3 a0 = { __shfl(eAf.x, s0, 64), __shfl(eAf.y, s0, 64), __shfl(eAf.z, s0, 64) };
        const F3 b0 = { __shfl(eBf.x, s0, 64), __shfl(eBf.y, s0, 64), __shfl(eBf.z, s0, 64) };
        const F3 a1 = { __shfl(eAf.x, s1, 64), __shfl(eAf.y, s1, 64), __shfl(eAf.z, s1, 64) };
        const F3 b1 = { __shfl(eBf.x, s1, 64), __shfl(eBf.y, s1, 64), __shfl(eBf.z, s1, 64) };
        ej0 = (j0 & 1) ? b0 : a0;
        ej1 = (j1 & 1) ? b1 : a1;
    }

    const F3 vvA = nrmf(crossf(ej0, uA));
    const F3 vvB = nrmf(crossf(ej1, uB));

    // ---- coalesced NT stores: 8B/lane contiguous per instruction (full-line WC) ----
    float* bu  = out + (size_t)b * (kNE*3);
    float* bv  = bu  + (size_t)kB * (kNE*3);
    float* kbo = bv  + (size_t)kB * (kNE*3);
    const int o = 6*lane;

    nts2(bu + o    , uA.x, uA.y);
    nts2(bu + o + 2, uA.z, uB.x);
    nts2(bu + o + 4, uB.y, uB.z);

    nts2(bv + o    , vvA.x, vvA.y);
    nts2(bv + o + 2, vvA.z, vvB.x);
    nts2(bv + o + 4, vvB.y, vvB.z);

    nts2(kbo + o    , kb0.x, kb0.y);
    nts2(kbo + o + 2, kb0.z, kb1.x);
    nts2(kbo + o + 4, kb1.y, kb1.z);
}

} // namespace

extern "C" void kernel_launch(void* const* d_in, const int* in_sizes, int n_in,
                              void* d_out, int out_size, void* d_ws, size_t ws_size,
                              hipStream_t stream)
{
    const float* verts = (const float*)d_in[0];
    const float* dinit = (const float*)d_in[1];
    const float* restL = (const float*)d_in[2];
    float* out = (float*)d_out;

    dim3 grid(kB / kRPB);     // 1024 blocks x 16 waves = 16384 rods
    dim3 block(64 * kRPB);    // 1024 threads
    hipLaunchKernelGGL(rod_frames_scan_kernel, grid, block, 0, stream,
                       verts, dinit, restL, out);
}